// Round 5
// baseline (175.113 us; speedup 1.0000x reference)
//
#include <hip/hip_runtime.h>
#include <hip/hip_bf16.h>

// STU spectral conv. out[b,t,d] = 2 * sum_{j even} phi_proj[j,d] x_proj[b,t-j,d].
// Even/odd time split packed as complex -> one FFT-4096 per (b,d).
// FFT-4096 = radix-16^3 register FFT, 256 threads, 16 cplx/thread.
// R5: (a) GEMM restored to global_load_lds (exonerated: r2/r3 both failed
// with identical absmax -> bug was conv OOB, not staging); (b) all twiddles
// from one 32KB global table T1[p][t]=e^{-2pi i pt/4096} (no trig in conv);
// (c) zero-pad + output-truncation specializations; (d) outT in bf16;
// (e) tiled Mi transpose; (f) phi_proj fused into filter_fft.

#define NB 4
#define NS 4096
#define ND 768
#define NK 24

typedef __attribute__((ext_vector_type(8))) short short8;
typedef __attribute__((ext_vector_type(4))) float f32x4;
typedef __attribute__((ext_vector_type(4))) unsigned short u16x4;

static __device__ __forceinline__ float bf2f(unsigned short u) {
  union { unsigned int i; float f; } v; v.i = ((unsigned int)u) << 16; return v.f;
}
static __device__ __forceinline__ unsigned short f2bf(float f) {
  union { float f; unsigned int i; } v; v.f = f;
  return (unsigned short)((v.i + 0x7fffu + ((v.i >> 16) & 1u)) >> 16);
}

__device__ __forceinline__ float2 cadd(float2 a, float2 b){ return make_float2(a.x+b.x, a.y+b.y); }
__device__ __forceinline__ float2 csub(float2 a, float2 b){ return make_float2(a.x-b.x, a.y-b.y); }
__device__ __forceinline__ float2 cmul(float2 a, float2 b){ return make_float2(a.x*b.x-a.y*b.y, a.x*b.y+a.y*b.x); }
// a * conj(b)
__device__ __forceinline__ float2 cmulc(float2 a, float2 b){ return make_float2(a.x*b.x+a.y*b.y, a.y*b.x-a.x*b.y); }

#define C4 0.70710678118654752f
#define C8 0.92387953251128674f
#define S8 0.38268343236508977f
#define TWO_PI 6.28318530717958648f

// DIF 16-pt: natural input, output reg r holds X[bitrev4(r)]
__device__ __forceinline__ void fft16_dif(float2 v[16]) {
  const float twr[8] = {1.f, C8, C4, S8, 0.f, -S8, -C4, -C8};
  const float twi[8] = {0.f, -S8, -C4, -C8, -1.f, -C8, -C4, -S8};
#pragma unroll
  for (int i = 0; i < 8; ++i) {                       // m=8
    float2 a = v[i], b = v[i+8];
    v[i] = cadd(a, b);
    float2 d = csub(a, b);
    v[i+8] = make_float2(d.x*twr[i]-d.y*twi[i], d.x*twi[i]+d.y*twr[i]);
  }
#pragma unroll
  for (int blk = 0; blk < 16; blk += 8)               // m=4
#pragma unroll
    for (int i = 0; i < 4; ++i) {
      float2 a = v[blk+i], b = v[blk+i+4];
      v[blk+i] = cadd(a, b);
      float2 d = csub(a, b);
      v[blk+i+4] = make_float2(d.x*twr[2*i]-d.y*twi[2*i], d.x*twi[2*i]+d.y*twr[2*i]);
    }
#pragma unroll
  for (int blk = 0; blk < 16; blk += 4) {             // m=2 (tw: 1, -i)
    { float2 a = v[blk],   b = v[blk+2]; v[blk] = cadd(a,b);   v[blk+2] = csub(a,b); }
    { float2 a = v[blk+1], b = v[blk+3]; float2 d = csub(a,b);
      v[blk+1] = cadd(a,b); v[blk+3] = make_float2(d.y, -d.x); }
  }
#pragma unroll
  for (int blk = 0; blk < 16; blk += 2) {             // m=1
    float2 a = v[blk], b = v[blk+1];
    v[blk] = cadd(a, b); v[blk+1] = csub(a, b);
  }
}

// same but input v[8..15] known zero (zero-padded signal): first stage is a copy+twiddle
__device__ __forceinline__ void fft16_dif_zero8(float2 v[16]) {
  const float twr[8] = {1.f, C8, C4, S8, 0.f, -S8, -C4, -C8};
  const float twi[8] = {0.f, -S8, -C4, -C8, -1.f, -C8, -C4, -S8};
#pragma unroll
  for (int i = 1; i < 8; ++i) {                       // m=8, b=0: v[i+8]=v[i]*tw
    float2 a = v[i];
    v[i+8] = make_float2(a.x*twr[i]-a.y*twi[i], a.x*twi[i]+a.y*twr[i]);
  }
  v[8] = v[0];
#pragma unroll
  for (int blk = 0; blk < 16; blk += 8)               // m=4
#pragma unroll
    for (int i = 0; i < 4; ++i) {
      float2 a = v[blk+i], b = v[blk+i+4];
      v[blk+i] = cadd(a, b);
      float2 d = csub(a, b);
      v[blk+i+4] = make_float2(d.x*twr[2*i]-d.y*twi[2*i], d.x*twi[2*i]+d.y*twr[2*i]);
    }
#pragma unroll
  for (int blk = 0; blk < 16; blk += 4) {             // m=2
    { float2 a = v[blk],   b = v[blk+2]; v[blk] = cadd(a,b);   v[blk+2] = csub(a,b); }
    { float2 a = v[blk+1], b = v[blk+3]; float2 d = csub(a,b);
      v[blk+1] = cadd(a,b); v[blk+3] = make_float2(d.y, -d.x); }
  }
#pragma unroll
  for (int blk = 0; blk < 16; blk += 2) {             // m=1
    float2 a = v[blk], b = v[blk+1];
    v[blk] = cadd(a, b); v[blk+1] = csub(a, b);
  }
}

// conj-transpose mirror (unnormalized): input reg r = X[bitrev4(r)],
// output natural y[n] = sum_k X[k] W^{+nk}
__device__ __forceinline__ void idft16(float2 v[16]) {
  const float twr[8] = {1.f, C8, C4, S8, 0.f, -S8, -C4, -C8};
  const float twi[8] = {0.f, S8, C4, C8, 1.f, C8, C4, S8};     // conj
#pragma unroll
  for (int blk = 0; blk < 16; blk += 2) {             // m=1
    float2 a = v[blk], b = v[blk+1];
    v[blk] = cadd(a, b); v[blk+1] = csub(a, b);
  }
#pragma unroll
  for (int blk = 0; blk < 16; blk += 4) {             // m=2 (tw: 1, +i)
    { float2 a = v[blk],   b = v[blk+2]; v[blk] = cadd(a,b);   v[blk+2] = csub(a,b); }
    { float2 a = v[blk+1], b = v[blk+3]; float2 t = make_float2(-b.y, b.x);
      v[blk+1] = cadd(a,t); v[blk+3] = csub(a,t); }
  }
#pragma unroll
  for (int blk = 0; blk < 16; blk += 8)               // m=4
#pragma unroll
    for (int i = 0; i < 4; ++i) {
      float2 b = v[blk+i+4];
      float2 t = make_float2(b.x*twr[2*i]-b.y*twi[2*i], b.x*twi[2*i]+b.y*twr[2*i]);
      float2 a = v[blk+i];
      v[blk+i] = cadd(a, t); v[blk+i+4] = csub(a, t);
    }
#pragma unroll
  for (int i = 0; i < 8; ++i) {                       // m=8
    float2 b = v[i+8];
    float2 t = make_float2(b.x*twr[i]-b.y*twi[i], b.x*twi[i]+b.y*twr[i]);
    float2 a = v[i];
    v[i] = cadd(a, t); v[i+8] = csub(a, t);
  }
}

// idft16 but only outputs 0..7 are needed: last stage skips the subtract half
__device__ __forceinline__ void idft16_low8(float2 v[16]) {
  const float twr[8] = {1.f, C8, C4, S8, 0.f, -S8, -C4, -C8};
  const float twi[8] = {0.f, S8, C4, C8, 1.f, C8, C4, S8};
#pragma unroll
  for (int blk = 0; blk < 16; blk += 2) {
    float2 a = v[blk], b = v[blk+1];
    v[blk] = cadd(a, b); v[blk+1] = csub(a, b);
  }
#pragma unroll
  for (int blk = 0; blk < 16; blk += 4) {
    { float2 a = v[blk],   b = v[blk+2]; v[blk] = cadd(a,b);   v[blk+2] = csub(a,b); }
    { float2 a = v[blk+1], b = v[blk+3]; float2 t = make_float2(-b.y, b.x);
      v[blk+1] = cadd(a,t); v[blk+3] = csub(a,t); }
  }
#pragma unroll
  for (int blk = 0; blk < 16; blk += 8)
#pragma unroll
    for (int i = 0; i < 4; ++i) {
      float2 b = v[blk+i+4];
      float2 t = make_float2(b.x*twr[2*i]-b.y*twi[2*i], b.x*twi[2*i]+b.y*twr[2*i]);
      float2 a = v[blk+i];
      v[blk+i] = cadd(a, t); v[blk+i+4] = csub(a, t);
    }
#pragma unroll
  for (int i = 0; i < 8; ++i) {                       // m=8: only y[i]=a+t needed
    float2 b = v[i+8];
    float2 t = make_float2(b.x*twr[i]-b.y*twi[i], b.x*twi[i]+b.y*twr[i]);
    v[i] = cadd(v[i], t);
  }
}

#define BR_TABLE {0,8,4,12,2,10,6,14,1,9,5,13,3,11,7,15}
#define PAD(i) ((i) + ((i) >> 4))

// ---------------- twiddle table T1[p*256+t] = e^{-2pi i p t / 4096} ----------------
__global__ __launch_bounds__(256) void twiddle_init(float2* __restrict__ T1) {
  int idx = blockIdx.x * 256 + threadIdx.x;   // p*256+t
  int p = idx >> 8, t = idx & 255;
  float ang = -(TWO_PI / 4096.f) * (float)(p * t);
  float sn, cs;
  __sincosf(ang, &sn, &cs);
  T1[idx] = make_float2(cs, sn);
}

// ---------------- cast x (fp32 -> bf16) ----------------
__global__ __launch_bounds__(256) void cast_x_bf16(const float* __restrict__ in,
                                                   unsigned short* __restrict__ out) {
  int i = (blockIdx.x * 256 + threadIdx.x) * 4;
  float4 v = *(const float4*)(in + i);
  u16x4 o = { f2bf(v.x), f2bf(v.y), f2bf(v.z), f2bf(v.w) };
  *(u16x4*)(out + i) = o;
}

// ---------------- MiT[d][e] = bf16(Mi[e][d]), LDS-tiled ----------------
__global__ __launch_bounds__(256) void transpose_cast_Mi(const float* __restrict__ Mi,
                                                         unsigned short* __restrict__ MiT) {
  __shared__ float tile[64][65];
  const int d0 = blockIdx.x * 64;
  const int e0 = blockIdx.y * 64;
  const int tid = threadIdx.x;
#pragma unroll
  for (int i = 0; i < 16; ++i) {
    int ee = (tid >> 6) + i * 4;
    int dd = tid & 63;
    tile[ee][dd] = Mi[(e0 + ee) * ND + d0 + dd];
  }
  __syncthreads();
#pragma unroll
  for (int i = 0; i < 8; ++i) {
    int dd = (tid >> 5) + i * 8;
    int ee2 = (tid & 31) * 2;
    unsigned int w = (unsigned int)f2bf(tile[ee2][dd]) |
                     ((unsigned int)f2bf(tile[ee2 + 1][dd]) << 16);
    *(unsigned int*)(MiT + (size_t)(d0 + dd) * ND + e0 + ee2) = w;
  }
}

// ---------------- GEMM: x_projT[b,d,s] via mfma + global_load_lds ----------------
__global__ __launch_bounds__(256) void gemm_xprojT(const unsigned short* __restrict__ Xb,
                                                   const unsigned short* __restrict__ MiT,
                                                   unsigned short* __restrict__ XPT) {
  __shared__ unsigned short As[128 * 32];
  __shared__ unsigned short Bs[128 * 32];
  const int tid = threadIdx.x;
  const int lane = tid & 63;
  const int wave = tid >> 6;
  const int c0 = blockIdx.x * 128;      // d (6 col-blocks; consecutive share A-tile in L2)
  const int r0 = blockIdx.y * 128;      // row in [0,16384)
  const int wr = (wave >> 1) * 64;
  const int wc = (wave & 1) * 64;

  f32x4 acc[4][4];
#pragma unroll
  for (int m = 0; m < 4; ++m)
#pragma unroll
    for (int n = 0; n < 4; ++n) acc[m][n] = (f32x4){0.f, 0.f, 0.f, 0.f};

  const int ldRow = (lane >> 2);        // 0..15 within 16-row chunk
  const int ldK = (lane & 3) * 8;       // short offset within 32-wide k

  for (int k0 = 0; k0 < ND; k0 += 32) {
    if (k0) __syncthreads();
#pragma unroll
    for (int h = 0; h < 2; ++h) {
      int c = wave * 2 + h;             // chunk 0..7, 16 rows each
      int row = c * 16 + ldRow;
      const unsigned short* ga = Xb + (size_t)(r0 + row) * ND + k0 + ldK;
      const unsigned short* gb = MiT + (size_t)(c0 + row) * ND + k0 + ldK;
      __builtin_amdgcn_global_load_lds(
          (const __attribute__((address_space(1))) void*)ga,
          (__attribute__((address_space(3))) void*)(As + c * 512), 16, 0, 0);
      __builtin_amdgcn_global_load_lds(
          (const __attribute__((address_space(1))) void*)gb,
          (__attribute__((address_space(3))) void*)(Bs + c * 512), 16, 0, 0);
    }
    __syncthreads();

    short8 a[4], b[4];
#pragma unroll
    for (int m = 0; m < 4; ++m)
      a[m] = *(const short8*)(As + (wr + m * 16 + (lane & 15)) * 32 + (lane >> 4) * 8);
#pragma unroll
    for (int n = 0; n < 4; ++n)
      b[n] = *(const short8*)(Bs + (wc + n * 16 + (lane & 15)) * 32 + (lane >> 4) * 8);
#pragma unroll
    for (int m = 0; m < 4; ++m)
#pragma unroll
      for (int n = 0; n < 4; ++n)
        acc[m][n] = __builtin_amdgcn_mfma_f32_16x16x32_bf16(a[m], b[n], acc[m][n], 0, 0, 0);
  }

  const int bI = r0 >> 12;
  const int sBase = r0 & (NS - 1);
#pragma unroll
  for (int m = 0; m < 4; ++m) {
#pragma unroll
    for (int n = 0; n < 4; ++n) {
      int col = c0 + wc + n * 16 + (lane & 15);
      int srow = sBase + wr + m * 16 + (lane >> 4) * 4;
      f32x4 v = acc[m][n];
      u16x4 o = { f2bf(v[0]), f2bf(v[1]), f2bf(v[2]), f2bf(v[3]) };
      *(u16x4*)(XPT + ((size_t)bI * ND + col) * NS + srow) = o;
    }
  }
}

// ---------------- filter spectra (fused phi projection) ----------------
// H[d][r*256+tid] = fft4096(h_d)*(2/4096), h_d[m] = sum_k phi[2m,k] Mf[k,d]
__global__ __launch_bounds__(256) void filter_fft(const float* __restrict__ phi,
                                                  const float* __restrict__ Mf,
                                                  const float2* __restrict__ T1,
                                                  float2* __restrict__ Hbr) {
  __shared__ float LR[4352], LI[4352];
  const int d = blockIdx.x;
  const int tid = threadIdx.x;
  const int BR[16] = BR_TABLE;
  float2 v[16];

  float mf[NK];
#pragma unroll
  for (int k = 0; k < NK; ++k) mf[k] = Mf[k * ND + d];   // block-uniform -> s_loads
#pragma unroll
  for (int n2 = 0; n2 < 8; ++n2) {
    int m = n2 * 256 + tid;            // 0..2047
    const float* pr = phi + (size_t)(2 * m) * NK;
    float acc = 0.f;
#pragma unroll
    for (int k = 0; k < NK; ++k) acc += pr[k] * mf[k];
    v[n2] = make_float2(acc, 0.f);
  }
#pragma unroll
  for (int n2 = 8; n2 < 16; ++n2) v[n2] = make_float2(0.f, 0.f);

  // P1: DFT over n2 -> pa, twiddle T1[pa][tid], slot pa*256+tid
  fft16_dif_zero8(v);
#pragma unroll
  for (int p = 1; p < 16; ++p) v[BR[p]] = cmul(v[BR[p]], T1[p * 256 + tid]);
#pragma unroll
  for (int r = 0; r < 16; ++r) { int i = BR[r] * 256 + tid; int s = PAD(i); LR[s] = v[r].x; LI[s] = v[r].y; }
  __syncthreads();

  // P2: thread (pa,n0), DFT over n1 -> pb, twiddle T1[pb][16*n0]
  const int p2 = tid >> 4, n0 = tid & 15;
#pragma unroll
  for (int n1 = 0; n1 < 16; ++n1) { int i = p2 * 256 + n1 * 16 + n0; int s = PAD(i); v[n1] = make_float2(LR[s], LI[s]); }
  fft16_dif(v);
#pragma unroll
  for (int p = 1; p < 16; ++p) v[BR[p]] = cmul(v[BR[p]], T1[p * 256 + 16 * n0]);
  __syncthreads();
#pragma unroll
  for (int r = 0; r < 16; ++r) { int i = p2 * 256 + BR[r] * 16 + n0; int s = PAD(i); LR[s] = v[r].x; LI[s] = v[r].y; }
  __syncthreads();

  // P3: thread (pa,pb)=tid, DFT over n0 -> pc (regs); store lane-coalesced
#pragma unroll
  for (int q = 0; q < 16; ++q) { int i = tid * 16 + q; int s = PAD(i); v[q] = make_float2(LR[s], LI[s]); }
  fft16_dif(v);
  const float sc = 2.0f / 4096.0f;
  float2* H = Hbr + (size_t)d * 4096;
#pragma unroll
  for (int r = 0; r < 16; ++r)
    H[r * 256 + tid] = make_float2(v[r].x * sc, v[r].y * sc);
}

// ---------------- main conv: one (b,d) per workgroup ----------------
__global__ __launch_bounds__(256) void conv_kernel(const unsigned short* __restrict__ XPT,
                                                   const float2* __restrict__ Hbr,
                                                   const float2* __restrict__ T1,
                                                   unsigned int* __restrict__ outTb) {
  __shared__ float LR[4352], LI[4352];
  const int bd = blockIdx.x;
  const int d = bd % ND;
  const int tid = threadIdx.x;
  const int BR[16] = BR_TABLE;
  float2 v[16];

  // load: z[n] = (x[2n], x[2n+1]) bf16 pair as one dword; n >= 2048 zero
  const unsigned int* src = (const unsigned int*)(XPT + (size_t)bd * NS);
#pragma unroll
  for (int n2 = 0; n2 < 8; ++n2) {
    unsigned int w = src[n2 * 256 + tid];
    v[n2] = make_float2(bf2f((unsigned short)(w & 0xffffu)), bf2f((unsigned short)(w >> 16)));
  }
#pragma unroll
  for (int n2 = 8; n2 < 16; ++n2) v[n2] = make_float2(0.f, 0.f);

  // ---- forward P1 ----
  fft16_dif_zero8(v);
#pragma unroll
  for (int p = 1; p < 16; ++p) v[BR[p]] = cmul(v[BR[p]], T1[p * 256 + tid]);
#pragma unroll
  for (int r = 0; r < 16; ++r) { int i = BR[r] * 256 + tid; int s = PAD(i); LR[s] = v[r].x; LI[s] = v[r].y; }
  __syncthreads();

  // ---- forward P2 ----
  const int p2 = tid >> 4, n0 = tid & 15;
#pragma unroll
  for (int n1 = 0; n1 < 16; ++n1) { int i = p2 * 256 + n1 * 16 + n0; int s = PAD(i); v[n1] = make_float2(LR[s], LI[s]); }
  fft16_dif(v);
#pragma unroll
  for (int p = 1; p < 16; ++p) v[BR[p]] = cmul(v[BR[p]], T1[p * 256 + 16 * n0]);
  __syncthreads();
#pragma unroll
  for (int r = 0; r < 16; ++r) { int i = p2 * 256 + BR[r] * 16 + n0; int s = PAD(i); LR[s] = v[r].x; LI[s] = v[r].y; }
  __syncthreads();

  // ---- forward P3 + pointwise*H + inverse PA: all in registers ----
#pragma unroll
  for (int q = 0; q < 16; ++q) { int i = tid * 16 + q; int s = PAD(i); v[q] = make_float2(LR[s], LI[s]); }
  fft16_dif(v);
  const float2* H = Hbr + (size_t)d * 4096;
#pragma unroll
  for (int r = 0; r < 16; ++r) v[r] = cmul(v[r], H[r * 256 + tid]);
  idft16(v);                                   // -> natural over pc-axis
  // PA twiddle: e^{+2pi i pb n/256} = conj(T1[n][16*pb]), pb = tid&15
#pragma unroll
  for (int n = 1; n < 16; ++n) v[n] = cmulc(v[n], T1[n * 256 + 16 * (tid & 15)]);
#pragma unroll
  for (int n = 0; n < 16; ++n) { int i = tid * 16 + n; int s = PAD(i); LR[s] = v[n].x; LI[s] = v[n].y; }
  __syncthreads();

  // ---- inverse PB: thread (pa,n0), IDFT over pb -> n1 ----
#pragma unroll
  for (int r = 0; r < 16; ++r) { int i = p2 * 256 + BR[r] * 16 + n0; int s = PAD(i); v[r] = make_float2(LR[s], LI[s]); }
  idft16(v);                                   // -> natural n1
  // PB twiddle: e^{+2pi i (16n+n0) pa/4096} = conj(T1[pa][16n+n0]), pa = p2
#pragma unroll
  for (int n = 0; n < 16; ++n) v[n] = cmulc(v[n], T1[p2 * 256 + 16 * n + n0]);
  __syncthreads();
#pragma unroll
  for (int n = 0; n < 16; ++n) { int i = p2 * 256 + n * 16 + n0; int s = PAD(i); LR[s] = v[n].x; LI[s] = v[n].y; }
  __syncthreads();

  // ---- inverse PC: thread tid, IDFT over pa -> natural n2 (only n2<8 needed) ----
#pragma unroll
  for (int r = 0; r < 16; ++r) { int i = BR[r] * 256 + tid; int s = PAD(i); v[r] = make_float2(LR[s], LI[s]); }
  idft16_low8(v);
  unsigned int* dst = outTb + (size_t)bd * 2048;    // dword = (out[2n], out[2n+1]) bf16
#pragma unroll
  for (int n2 = 0; n2 < 8; ++n2) {
    float2 y = v[n2];
    unsigned int w = (unsigned int)f2bf(y.x) | ((unsigned int)f2bf(y.y) << 16);
    dst[(n2 << 8) + tid] = w;
  }
}

// ---------------- transpose outTb (B,D,S) bf16 -> out (B,S,D) fp32 ----------------
__global__ __launch_bounds__(256) void transpose_out(const unsigned int* __restrict__ outTb,
                                                     float* __restrict__ out) {
  __shared__ float tile[64][65];
  const int b = blockIdx.z;
  const int d0 = blockIdx.y * 64;
  const int s0 = blockIdx.x * 64;
  const int tid = threadIdx.x;
#pragma unroll
  for (int i = 0; i < 8; ++i) {
    int dd = (tid >> 5) + i * 8;
    int ss2 = (tid & 31) * 2;
    unsigned int w = outTb[(((size_t)b * ND + d0 + dd) * NS + s0 + ss2) >> 1];
    tile[dd][ss2]     = bf2f((unsigned short)(w & 0xffffu));
    tile[dd][ss2 + 1] = bf2f((unsigned short)(w >> 16));
  }
  __syncthreads();
#pragma unroll
  for (int i = 0; i < 16; ++i) {
    int ss = (tid >> 6) + i * 4;
    int dd = tid & 63;
    out[((size_t)b * NS + s0 + ss) * ND + d0 + dd] = tile[dd][ss];
  }
}

extern "C" void kernel_launch(void* const* d_in, const int* in_sizes, int n_in,
                              void* d_out, int out_size, void* d_ws, size_t ws_size,
                              hipStream_t stream) {
  const float* x   = (const float*)d_in[0];
  const float* phi = (const float*)d_in[1];
  const float* Mi  = (const float*)d_in[2];
  const float* Mf  = (const float*)d_in[3];
  float* out = (float*)d_out;

  // ws (96 MB): XPT bf16 @0 (24M) | Hbr @24M (24M) | pool @48M (48M)
  // pool: outTb bf16 @0 (24M, overlaps dead xbf) == xbf @0 (24M) | MiT @24M | T1 @26M
  const size_t SZ_XPT = (size_t)NB * ND * NS * 2;        // 24 MB
  const size_t SZ_HBR = (size_t)ND * 4096 * 8;           // 24 MB
  const size_t SZ_POOL = (size_t)NB * ND * NS * 4;       // 48 MB
  if (ws_size < SZ_XPT + SZ_HBR + SZ_POOL) return;

  char* ws = (char*)d_ws;
  unsigned short* xprojT = (unsigned short*)ws;
  float2* Hbr = (float2*)(ws + SZ_XPT);
  char* pool = ws + SZ_XPT + SZ_HBR;
  unsigned short* xbf = (unsigned short*)pool;           // phase 1 (cast->gemm)
  unsigned int* outTb = (unsigned int*)pool;             // phase 2 (conv->transpose)
  unsigned short* MiT = (unsigned short*)(pool + 25165824);
  float2* T1 = (float2*)(pool + 25165824 + 2097152);     // 32 KB

  cast_x_bf16<<<(NB * NS * ND) / (256 * 4), 256, 0, stream>>>(x, xbf);
  transpose_cast_Mi<<<dim3(ND / 64, ND / 64), 256, 0, stream>>>(Mi, MiT);
  twiddle_init<<<16, 256, 0, stream>>>(T1);
  gemm_xprojT<<<dim3(ND / 128, (NB * NS) / 128), 256, 0, stream>>>(xbf, MiT, xprojT);
  filter_fft<<<ND, 256, 0, stream>>>(phi, Mf, T1, Hbr);
  conv_kernel<<<NB * ND, 256, 0, stream>>>(xprojT, Hbr, T1, outTb);
  transpose_out<<<dim3(NS / 64, ND / 64, NB), 256, 0, stream>>>(outTb, out);
}

// Round 6
// 135.524 us; speedup vs baseline: 1.2921x; 1.2921x over previous
//
#include <hip/hip_runtime.h>
#include <hip/hip_bf16.h>

// STU spectral conv. out[b,t,d] = 2 * sum_{j even} phi_proj[j,d] x_proj[b,t-j,d].
// Even/odd time split packed as complex -> one FFT-4096 per (b,d).
// FFT-4096 = radix-16^3 register FFT, 256 threads, 16 cplx/thread.
// R6: (a) twiddles from compact in-LDS tables TA[k]=W_4096^k, TB[k]=W_256^k
//     (k<256, 4KB; every twiddle = product of <=2 entries, indices <256) --
//     fixes R5's latency regression from L2-resident twiddle loads;
// (b) GEMM C-epilogue staged through LDS -> full-cacheline coalesced writes
//     (was 8B/lane scatter at 8KB stride = write amplification).

#define NB 4
#define NS 4096
#define ND 768
#define NK 24

typedef __attribute__((ext_vector_type(8))) short short8;
typedef __attribute__((ext_vector_type(4))) float f32x4;
typedef __attribute__((ext_vector_type(4))) unsigned short u16x4;

static __device__ __forceinline__ float bf2f(unsigned short u) {
  union { unsigned int i; float f; } v; v.i = ((unsigned int)u) << 16; return v.f;
}
static __device__ __forceinline__ unsigned short f2bf(float f) {
  union { float f; unsigned int i; } v; v.f = f;
  return (unsigned short)((v.i + 0x7fffu + ((v.i >> 16) & 1u)) >> 16);
}

__device__ __forceinline__ float2 cadd(float2 a, float2 b){ return make_float2(a.x+b.x, a.y+b.y); }
__device__ __forceinline__ float2 csub(float2 a, float2 b){ return make_float2(a.x-b.x, a.y-b.y); }
__device__ __forceinline__ float2 cmul(float2 a, float2 b){ return make_float2(a.x*b.x-a.y*b.y, a.x*b.y+a.y*b.x); }
// a * conj(b)
__device__ __forceinline__ float2 cmulc(float2 a, float2 b){ return make_float2(a.x*b.x+a.y*b.y, a.y*b.x-a.x*b.y); }

#define C4 0.70710678118654752f
#define C8 0.92387953251128674f
#define S8 0.38268343236508977f
#define TWO_PI 6.28318530717958648f

// DIF 16-pt: natural input, output reg r holds X[bitrev4(r)]
__device__ __forceinline__ void fft16_dif(float2 v[16]) {
  const float twr[8] = {1.f, C8, C4, S8, 0.f, -S8, -C4, -C8};
  const float twi[8] = {0.f, -S8, -C4, -C8, -1.f, -C8, -C4, -S8};
#pragma unroll
  for (int i = 0; i < 8; ++i) {                       // m=8
    float2 a = v[i], b = v[i+8];
    v[i] = cadd(a, b);
    float2 d = csub(a, b);
    v[i+8] = make_float2(d.x*twr[i]-d.y*twi[i], d.x*twi[i]+d.y*twr[i]);
  }
#pragma unroll
  for (int blk = 0; blk < 16; blk += 8)               // m=4
#pragma unroll
    for (int i = 0; i < 4; ++i) {
      float2 a = v[blk+i], b = v[blk+i+4];
      v[blk+i] = cadd(a, b);
      float2 d = csub(a, b);
      v[blk+i+4] = make_float2(d.x*twr[2*i]-d.y*twi[2*i], d.x*twi[2*i]+d.y*twr[2*i]);
    }
#pragma unroll
  for (int blk = 0; blk < 16; blk += 4) {             // m=2 (tw: 1, -i)
    { float2 a = v[blk],   b = v[blk+2]; v[blk] = cadd(a,b);   v[blk+2] = csub(a,b); }
    { float2 a = v[blk+1], b = v[blk+3]; float2 d = csub(a,b);
      v[blk+1] = cadd(a,b); v[blk+3] = make_float2(d.y, -d.x); }
  }
#pragma unroll
  for (int blk = 0; blk < 16; blk += 2) {             // m=1
    float2 a = v[blk], b = v[blk+1];
    v[blk] = cadd(a, b); v[blk+1] = csub(a, b);
  }
}

// same but input v[8..15] known zero (zero-padded signal)
__device__ __forceinline__ void fft16_dif_zero8(float2 v[16]) {
  const float twr[8] = {1.f, C8, C4, S8, 0.f, -S8, -C4, -C8};
  const float twi[8] = {0.f, -S8, -C4, -C8, -1.f, -C8, -C4, -S8};
#pragma unroll
  for (int i = 1; i < 8; ++i) {                       // m=8, b=0
    float2 a = v[i];
    v[i+8] = make_float2(a.x*twr[i]-a.y*twi[i], a.x*twi[i]+a.y*twr[i]);
  }
  v[8] = v[0];
#pragma unroll
  for (int blk = 0; blk < 16; blk += 8)               // m=4
#pragma unroll
    for (int i = 0; i < 4; ++i) {
      float2 a = v[blk+i], b = v[blk+i+4];
      v[blk+i] = cadd(a, b);
      float2 d = csub(a, b);
      v[blk+i+4] = make_float2(d.x*twr[2*i]-d.y*twi[2*i], d.x*twi[2*i]+d.y*twr[2*i]);
    }
#pragma unroll
  for (int blk = 0; blk < 16; blk += 4) {             // m=2
    { float2 a = v[blk],   b = v[blk+2]; v[blk] = cadd(a,b);   v[blk+2] = csub(a,b); }
    { float2 a = v[blk+1], b = v[blk+3]; float2 d = csub(a,b);
      v[blk+1] = cadd(a,b); v[blk+3] = make_float2(d.y, -d.x); }
  }
#pragma unroll
  for (int blk = 0; blk < 16; blk += 2) {             // m=1
    float2 a = v[blk], b = v[blk+1];
    v[blk] = cadd(a, b); v[blk+1] = csub(a, b);
  }
}

// conj-transpose mirror (unnormalized): input reg r = X[bitrev4(r)],
// output natural y[n] = sum_k X[k] W^{+nk}
__device__ __forceinline__ void idft16(float2 v[16]) {
  const float twr[8] = {1.f, C8, C4, S8, 0.f, -S8, -C4, -C8};
  const float twi[8] = {0.f, S8, C4, C8, 1.f, C8, C4, S8};     // conj
#pragma unroll
  for (int blk = 0; blk < 16; blk += 2) {             // m=1
    float2 a = v[blk], b = v[blk+1];
    v[blk] = cadd(a, b); v[blk+1] = csub(a, b);
  }
#pragma unroll
  for (int blk = 0; blk < 16; blk += 4) {             // m=2 (tw: 1, +i)
    { float2 a = v[blk],   b = v[blk+2]; v[blk] = cadd(a,b);   v[blk+2] = csub(a,b); }
    { float2 a = v[blk+1], b = v[blk+3]; float2 t = make_float2(-b.y, b.x);
      v[blk+1] = cadd(a,t); v[blk+3] = csub(a,t); }
  }
#pragma unroll
  for (int blk = 0; blk < 16; blk += 8)               // m=4
#pragma unroll
    for (int i = 0; i < 4; ++i) {
      float2 b = v[blk+i+4];
      float2 t = make_float2(b.x*twr[2*i]-b.y*twi[2*i], b.x*twi[2*i]+b.y*twr[2*i]);
      float2 a = v[blk+i];
      v[blk+i] = cadd(a, t); v[blk+i+4] = csub(a, t);
    }
#pragma unroll
  for (int i = 0; i < 8; ++i) {                       // m=8
    float2 b = v[i+8];
    float2 t = make_float2(b.x*twr[i]-b.y*twi[i], b.x*twi[i]+b.y*twr[i]);
    float2 a = v[i];
    v[i] = cadd(a, t); v[i+8] = csub(a, t);
  }
}

// idft16 but only outputs 0..7 needed: last stage skips subtract half
__device__ __forceinline__ void idft16_low8(float2 v[16]) {
  const float twr[8] = {1.f, C8, C4, S8, 0.f, -S8, -C4, -C8};
  const float twi[8] = {0.f, S8, C4, C8, 1.f, C8, C4, S8};
#pragma unroll
  for (int blk = 0; blk < 16; blk += 2) {
    float2 a = v[blk], b = v[blk+1];
    v[blk] = cadd(a, b); v[blk+1] = csub(a, b);
  }
#pragma unroll
  for (int blk = 0; blk < 16; blk += 4) {
    { float2 a = v[blk],   b = v[blk+2]; v[blk] = cadd(a,b);   v[blk+2] = csub(a,b); }
    { float2 a = v[blk+1], b = v[blk+3]; float2 t = make_float2(-b.y, b.x);
      v[blk+1] = cadd(a,t); v[blk+3] = csub(a,t); }
  }
#pragma unroll
  for (int blk = 0; blk < 16; blk += 8)
#pragma unroll
    for (int i = 0; i < 4; ++i) {
      float2 b = v[blk+i+4];
      float2 t = make_float2(b.x*twr[2*i]-b.y*twi[2*i], b.x*twi[2*i]+b.y*twr[2*i]);
      float2 a = v[blk+i];
      v[blk+i] = cadd(a, t); v[blk+i+4] = csub(a, t);
    }
#pragma unroll
  for (int i = 0; i < 8; ++i) {                       // m=8: only y[i]=a+t
    float2 b = v[i+8];
    float2 t = make_float2(b.x*twr[i]-b.y*twi[i], b.x*twi[i]+b.y*twr[i]);
    v[i] = cadd(v[i], t);
  }
}

#define BR_TABLE {0,8,4,12,2,10,6,14,1,9,5,13,3,11,7,15}
#define PAD(i) ((i) + ((i) >> 4))

// ---------------- cast x (fp32 -> bf16) ----------------
__global__ __launch_bounds__(256) void cast_x_bf16(const float* __restrict__ in,
                                                   unsigned short* __restrict__ out) {
  int i = (blockIdx.x * 256 + threadIdx.x) * 4;
  float4 v = *(const float4*)(in + i);
  u16x4 o = { f2bf(v.x), f2bf(v.y), f2bf(v.z), f2bf(v.w) };
  *(u16x4*)(out + i) = o;
}

// ---------------- MiT[d][e] = bf16(Mi[e][d]), LDS-tiled ----------------
__global__ __launch_bounds__(256) void transpose_cast_Mi(const float* __restrict__ Mi,
                                                         unsigned short* __restrict__ MiT) {
  __shared__ float tile[64][65];
  const int d0 = blockIdx.x * 64;
  const int e0 = blockIdx.y * 64;
  const int tid = threadIdx.x;
#pragma unroll
  for (int i = 0; i < 16; ++i) {
    int ee = (tid >> 6) + i * 4;
    int dd = tid & 63;
    tile[ee][dd] = Mi[(e0 + ee) * ND + d0 + dd];
  }
  __syncthreads();
#pragma unroll
  for (int i = 0; i < 8; ++i) {
    int dd = (tid >> 5) + i * 8;
    int ee2 = (tid & 31) * 2;
    unsigned int w = (unsigned int)f2bf(tile[ee2][dd]) |
                     ((unsigned int)f2bf(tile[ee2 + 1][dd]) << 16);
    *(unsigned int*)(MiT + (size_t)(d0 + dd) * ND + e0 + ee2) = w;
  }
}

// ---------------- GEMM: x_projT[b,d,s], gload_lds staging + LDS-staged C-write ----------------
__global__ __launch_bounds__(256) void gemm_xprojT(const unsigned short* __restrict__ Xb,
                                                   const unsigned short* __restrict__ MiT,
                                                   unsigned short* __restrict__ XPT) {
  __shared__ __align__(16) unsigned char smem[33792];   // As|Bs (16KB) then Cb (33KB)
  unsigned short* As = (unsigned short*)smem;           // 128*32
  unsigned short* Bs = As + 128 * 32;                   // 128*32
  const int tid = threadIdx.x;
  const int lane = tid & 63;
  const int wave = tid >> 6;
  const int c0 = blockIdx.x * 128;      // d (6 col-blocks; consecutive share A-tile in L2)
  const int r0 = blockIdx.y * 128;      // row in [0,16384)
  const int wr = (wave >> 1) * 64;
  const int wc = (wave & 1) * 64;

  f32x4 acc[4][4];
#pragma unroll
  for (int m = 0; m < 4; ++m)
#pragma unroll
    for (int n = 0; n < 4; ++n) acc[m][n] = (f32x4){0.f, 0.f, 0.f, 0.f};

  const int ldRow = (lane >> 2);        // 0..15 within 16-row chunk
  const int ldK = (lane & 3) * 8;       // short offset within 32-wide k

  for (int k0 = 0; k0 < ND; k0 += 32) {
    if (k0) __syncthreads();
#pragma unroll
    for (int h = 0; h < 2; ++h) {
      int c = wave * 2 + h;             // chunk 0..7, 16 rows each
      int row = c * 16 + ldRow;
      const unsigned short* ga = Xb + (size_t)(r0 + row) * ND + k0 + ldK;
      const unsigned short* gb = MiT + (size_t)(c0 + row) * ND + k0 + ldK;
      __builtin_amdgcn_global_load_lds(
          (const __attribute__((address_space(1))) void*)ga,
          (__attribute__((address_space(3))) void*)(As + c * 512), 16, 0, 0);
      __builtin_amdgcn_global_load_lds(
          (const __attribute__((address_space(1))) void*)gb,
          (__attribute__((address_space(3))) void*)(Bs + c * 512), 16, 0, 0);
    }
    __syncthreads();

    short8 a[4], b[4];
#pragma unroll
    for (int m = 0; m < 4; ++m)
      a[m] = *(const short8*)(As + (wr + m * 16 + (lane & 15)) * 32 + (lane >> 4) * 8);
#pragma unroll
    for (int n = 0; n < 4; ++n)
      b[n] = *(const short8*)(Bs + (wc + n * 16 + (lane & 15)) * 32 + (lane >> 4) * 8);
#pragma unroll
    for (int m = 0; m < 4; ++m)
#pragma unroll
      for (int n = 0; n < 4; ++n)
        acc[m][n] = __builtin_amdgcn_mfma_f32_16x16x32_bf16(a[m], b[n], acc[m][n], 0, 0, 0);
  }

  // epilogue: bf16-pack into LDS (pitch 66 dwords: 2-way conflicts only),
  // then coalesced full-line global writes
  __syncthreads();                      // all waves done reading As/Bs
  unsigned int* Cb = (unsigned int*)smem;   // [128 cols][66]
#pragma unroll
  for (int m = 0; m < 4; ++m)
#pragma unroll
    for (int n = 0; n < 4; ++n) {
      int col = wc + n * 16 + (lane & 15);
      int sp = (wr + m * 16 + (lane >> 4) * 4) >> 1;   // even
      f32x4 a4 = acc[m][n];
      unsigned int w0 = (unsigned int)f2bf(a4[0]) | ((unsigned int)f2bf(a4[1]) << 16);
      unsigned int w1 = (unsigned int)f2bf(a4[2]) | ((unsigned int)f2bf(a4[3]) << 16);
      *(uint2*)(Cb + col * 66 + sp) = make_uint2(w0, w1);
    }
  __syncthreads();
  const int bI = r0 >> 12;
  const int sBase = r0 & (NS - 1);
  {
    int col = tid >> 1, half = tid & 1;
    const unsigned int* srcl = Cb + col * 66 + half * 32;
    unsigned int* dstg = (unsigned int*)(XPT + ((size_t)bI * ND + c0 + col) * NS + sBase) + half * 32;
#pragma unroll
    for (int k = 0; k < 8; ++k)
      *(uint4*)(dstg + k * 4) = *(const uint4*)(srcl + k * 4);
  }
}

// ---------------- filter spectra (fused phi projection, LDS twiddle tables) ----------------
__global__ __launch_bounds__(256) void filter_fft(const float* __restrict__ phi,
                                                  const float* __restrict__ Mf,
                                                  float2* __restrict__ Hbr) {
  __shared__ float LR[4352], LI[4352];
  __shared__ float2 TA[256], TB[256];
  const int d = blockIdx.x;
  const int tid = threadIdx.x;
  const int BR[16] = BR_TABLE;
  float2 v[16];

  {
    float sn, cs;
    __sincosf(-(TWO_PI / 4096.f) * (float)tid, &sn, &cs); TA[tid] = make_float2(cs, sn);
    __sincosf(-(TWO_PI / 256.f) * (float)tid, &sn, &cs);  TB[tid] = make_float2(cs, sn);
  }

  float mf[NK];
#pragma unroll
  for (int k = 0; k < NK; ++k) mf[k] = Mf[k * ND + d];
#pragma unroll
  for (int n2 = 0; n2 < 8; ++n2) {
    int m = n2 * 256 + tid;            // 0..2047
    const float* pr = phi + (size_t)(2 * m) * NK;
    float acc = 0.f;
#pragma unroll
    for (int k = 0; k < NK; ++k) acc += pr[k] * mf[k];
    v[n2] = make_float2(acc, 0.f);
  }
#pragma unroll
  for (int n2 = 8; n2 < 16; ++n2) v[n2] = make_float2(0.f, 0.f);

  fft16_dif_zero8(v);
  __syncthreads();                     // tables ready
  const int t1 = tid >> 4, t0 = tid & 15;
  // P1 twiddle: W_4096^{p*tid} = TB[p*t1] * TA[p*t0]
#pragma unroll
  for (int p = 1; p < 16; ++p) v[BR[p]] = cmul(v[BR[p]], cmul(TB[p * t1], TA[p * t0]));
#pragma unroll
  for (int r = 0; r < 16; ++r) { int i = BR[r] * 256 + tid; int s = PAD(i); LR[s] = v[r].x; LI[s] = v[r].y; }
  __syncthreads();

  // P2: thread (pa,n0), DFT over n1 -> pb, twiddle W_256^{n0*pb} = TB[n0*pb]
  const int p2 = tid >> 4, n0 = tid & 15;
#pragma unroll
  for (int n1 = 0; n1 < 16; ++n1) { int i = p2 * 256 + n1 * 16 + n0; int s = PAD(i); v[n1] = make_float2(LR[s], LI[s]); }
  fft16_dif(v);
#pragma unroll
  for (int p = 1; p < 16; ++p) v[BR[p]] = cmul(v[BR[p]], TB[p * n0]);
  __syncthreads();
#pragma unroll
  for (int r = 0; r < 16; ++r) { int i = p2 * 256 + BR[r] * 16 + n0; int s = PAD(i); LR[s] = v[r].x; LI[s] = v[r].y; }
  __syncthreads();

  // P3: thread (pa,pb)=tid, DFT over n0 -> pc (regs); store lane-coalesced
#pragma unroll
  for (int q = 0; q < 16; ++q) { int i = tid * 16 + q; int s = PAD(i); v[q] = make_float2(LR[s], LI[s]); }
  fft16_dif(v);
  const float sc = 2.0f / 4096.0f;
  float2* H = Hbr + (size_t)d * 4096;
#pragma unroll
  for (int r = 0; r < 16; ++r)
    H[r * 256 + tid] = make_float2(v[r].x * sc, v[r].y * sc);
}

// ---------------- main conv: one (b,d) per workgroup ----------------
__global__ __launch_bounds__(256) void conv_kernel(const unsigned short* __restrict__ XPT,
                                                   const float2* __restrict__ Hbr,
                                                   unsigned int* __restrict__ outTb) {
  __shared__ float LR[4352], LI[4352];
  __shared__ float2 TA[256], TB[256];
  const int bd = blockIdx.x;
  const int d = bd % ND;
  const int tid = threadIdx.x;
  const int BR[16] = BR_TABLE;
  float2 v[16];

  {
    float sn, cs;
    __sincosf(-(TWO_PI / 4096.f) * (float)tid, &sn, &cs); TA[tid] = make_float2(cs, sn);
    __sincosf(-(TWO_PI / 256.f) * (float)tid, &sn, &cs);  TB[tid] = make_float2(cs, sn);
  }

  // load: z[n] = (x[2n], x[2n+1]) bf16 pair as one dword; n >= 2048 zero
  const unsigned int* src = (const unsigned int*)(XPT + (size_t)bd * NS);
#pragma unroll
  for (int n2 = 0; n2 < 8; ++n2) {
    unsigned int w = src[n2 * 256 + tid];
    v[n2] = make_float2(bf2f((unsigned short)(w & 0xffffu)), bf2f((unsigned short)(w >> 16)));
  }
#pragma unroll
  for (int n2 = 8; n2 < 16; ++n2) v[n2] = make_float2(0.f, 0.f);

  // ---- forward P1 ----
  fft16_dif_zero8(v);
  __syncthreads();                     // twiddle tables ready
  const int t1 = tid >> 4, t0 = tid & 15;
#pragma unroll
  for (int p = 1; p < 16; ++p) v[BR[p]] = cmul(v[BR[p]], cmul(TB[p * t1], TA[p * t0]));
#pragma unroll
  for (int r = 0; r < 16; ++r) { int i = BR[r] * 256 + tid; int s = PAD(i); LR[s] = v[r].x; LI[s] = v[r].y; }
  __syncthreads();

  // ---- forward P2 ----
  const int p2 = tid >> 4, n0 = tid & 15;
#pragma unroll
  for (int n1 = 0; n1 < 16; ++n1) { int i = p2 * 256 + n1 * 16 + n0; int s = PAD(i); v[n1] = make_float2(LR[s], LI[s]); }
  fft16_dif(v);
#pragma unroll
  for (int p = 1; p < 16; ++p) v[BR[p]] = cmul(v[BR[p]], TB[p * n0]);
  __syncthreads();
#pragma unroll
  for (int r = 0; r < 16; ++r) { int i = p2 * 256 + BR[r] * 16 + n0; int s = PAD(i); LR[s] = v[r].x; LI[s] = v[r].y; }
  __syncthreads();

  // ---- forward P3 + pointwise*H + inverse PA: all in registers ----
#pragma unroll
  for (int q = 0; q < 16; ++q) { int i = tid * 16 + q; int s = PAD(i); v[q] = make_float2(LR[s], LI[s]); }
  fft16_dif(v);
  const float2* H = Hbr + (size_t)d * 4096;
#pragma unroll
  for (int r = 0; r < 16; ++r) v[r] = cmul(v[r], H[r * 256 + tid]);
  idft16(v);                                   // -> natural over pc-axis
  // PA twiddle: conj(W_256^{n*pb}), pb = tid&15
#pragma unroll
  for (int n = 1; n < 16; ++n) v[n] = cmulc(v[n], TB[n * (tid & 15)]);
#pragma unroll
  for (int n = 0; n < 16; ++n) { int i = tid * 16 + n; int s = PAD(i); LR[s] = v[n].x; LI[s] = v[n].y; }
  __syncthreads();

  // ---- inverse PB: thread (pa,n0), IDFT over pb -> n1 ----
#pragma unroll
  for (int r = 0; r < 16; ++r) { int i = p2 * 256 + BR[r] * 16 + n0; int s = PAD(i); v[r] = make_float2(LR[s], LI[s]); }
  idft16(v);                                   // -> natural n1
  // PB twiddle: conj(W_4096^{pa(16n+n0)}) = conj(TB[pa*n] * TA[pa*n0])
  {
    float2 cA = TA[p2 * n0];
#pragma unroll
    for (int n = 0; n < 16; ++n) v[n] = cmulc(v[n], cmul(TB[p2 * n], cA));
  }
  __syncthreads();
#pragma unroll
  for (int n = 0; n < 16; ++n) { int i = p2 * 256 + n * 16 + n0; int s = PAD(i); LR[s] = v[n].x; LI[s] = v[n].y; }
  __syncthreads();

  // ---- inverse PC: thread tid, IDFT over pa -> natural n2 (only n2<8 needed) ----
#pragma unroll
  for (int r = 0; r < 16; ++r) { int i = BR[r] * 256 + tid; int s = PAD(i); v[r] = make_float2(LR[s], LI[s]); }
  idft16_low8(v);
  unsigned int* dst = outTb + (size_t)bd * 2048;    // dword = (out[2n], out[2n+1]) bf16
#pragma unroll
  for (int n2 = 0; n2 < 8; ++n2) {
    float2 y = v[n2];
    unsigned int w = (unsigned int)f2bf(y.x) | ((unsigned int)f2bf(y.y) << 16);
    dst[(n2 << 8) + tid] = w;
  }
}

// ---------------- transpose outTb (B,D,S) bf16 -> out (B,S,D) fp32 ----------------
__global__ __launch_bounds__(256) void transpose_out(const unsigned int* __restrict__ outTb,
                                                     float* __restrict__ out) {
  __shared__ float tile[64][65];
  const int b = blockIdx.z;
  const int d0 = blockIdx.y * 64;
  const int s0 = blockIdx.x * 64;
  const int tid = threadIdx.x;
#pragma unroll
  for (int i = 0; i < 8; ++i) {
    int dd = (tid >> 5) + i * 8;
    int ss2 = (tid & 31) * 2;
    unsigned int w = outTb[(((size_t)b * ND + d0 + dd) * NS + s0 + ss2) >> 1];
    tile[dd][ss2]     = bf2f((unsigned short)(w & 0xffffu));
    tile[dd][ss2 + 1] = bf2f((unsigned short)(w >> 16));
  }
  __syncthreads();
#pragma unroll
  for (int i = 0; i < 16; ++i) {
    int ss = (tid >> 6) + i * 4;
    int dd = tid & 63;
    out[((size_t)b * NS + s0 + ss) * ND + d0 + dd] = tile[dd][ss];
  }
}

extern "C" void kernel_launch(void* const* d_in, const int* in_sizes, int n_in,
                              void* d_out, int out_size, void* d_ws, size_t ws_size,
                              hipStream_t stream) {
  const float* x   = (const float*)d_in[0];
  const float* phi = (const float*)d_in[1];
  const float* Mi  = (const float*)d_in[2];
  const float* Mf  = (const float*)d_in[3];
  float* out = (float*)d_out;

  // ws (96 MB): XPT bf16 @0 (24M) | Hbr @24M (24M) | pool @48M (48M)
  // pool: xbf (phase 1) / outTb (phase 2) overlap @0 (24M) | MiT @24M
  const size_t SZ_XPT = (size_t)NB * ND * NS * 2;        // 24 MB
  const size_t SZ_HBR = (size_t)ND * 4096 * 8;           // 24 MB
  const size_t SZ_POOL = (size_t)NB * ND * NS * 4;       // 48 MB
  if (ws_size < SZ_XPT + SZ_HBR + SZ_POOL) return;

  char* ws = (char*)d_ws;
  unsigned short* xprojT = (unsigned short*)ws;
  float2* Hbr = (float2*)(ws + SZ_XPT);
  char* pool = ws + SZ_XPT + SZ_HBR;
  unsigned short* xbf = (unsigned short*)pool;           // phase 1 (cast->gemm)
  unsigned int* outTb = (unsigned int*)pool;             // phase 2 (conv->transpose)
  unsigned short* MiT = (unsigned short*)(pool + 25165824);

  cast_x_bf16<<<(NB * NS * ND) / (256 * 4), 256, 0, stream>>>(x, xbf);
  transpose_cast_Mi<<<dim3(ND / 64, ND / 64), 256, 0, stream>>>(Mi, MiT);
  gemm_xprojT<<<dim3(ND / 128, (NB * NS) / 128), 256, 0, stream>>>(xbf, MiT, xprojT);
  filter_fft<<<ND, 256, 0, stream>>>(phi, Mf, Hbr);
  conv_kernel<<<NB * ND, 256, 0, stream>>>(xprojT, Hbr, outTb);
  transpose_out<<<dim3(NS / 64, ND / 64, NB), 256, 0, stream>>>(outTb, out);
}

// Round 7
// 126.249 us; speedup vs baseline: 1.3871x; 1.0735x over previous
//
#include <hip/hip_runtime.h>
#include <hip/hip_bf16.h>

// STU spectral conv. out[b,t,d] = 2 * sum_{j even} phi_proj[j,d] x_proj[b,t-j,d].
// Even/odd time split packed as complex -> one FFT-4096 per (b,d).
// FFT-4096 = radix-16^3 register FFT, 256 threads, 16 cplx/thread.
// R7: GEMM rework (single-area round):
//  - 2-phase prefetch loop (issue tile t+1 loads before computing tile t,
//    double-buffered LDS, one barrier/iter) -- m97 structure;
//  - fp32 x read directly, cast fused into A-staging (cast_x kernel removed);
//  - XCD-chunk swizzle (768%8==0, bijective): 6 blocks sharing an A-panel
//    land on one XCD's L2;
//  - LDS-staged coalesced C epilogue kept from R6.
// conv/filter/transposes unchanged from R6 (conv ~49us, VALU-bound 77%).

#define NB 4
#define NS 4096
#define ND 768
#define NK 24

typedef __attribute__((ext_vector_type(8))) short short8;
typedef __attribute__((ext_vector_type(4))) float f32x4;
typedef __attribute__((ext_vector_type(4))) unsigned short u16x4;

static __device__ __forceinline__ float bf2f(unsigned short u) {
  union { unsigned int i; float f; } v; v.i = ((unsigned int)u) << 16; return v.f;
}
static __device__ __forceinline__ unsigned short f2bf(float f) {
  union { float f; unsigned int i; } v; v.f = f;
  return (unsigned short)((v.i + 0x7fffu + ((v.i >> 16) & 1u)) >> 16);
}

__device__ __forceinline__ float2 cadd(float2 a, float2 b){ return make_float2(a.x+b.x, a.y+b.y); }
__device__ __forceinline__ float2 csub(float2 a, float2 b){ return make_float2(a.x-b.x, a.y-b.y); }
__device__ __forceinline__ float2 cmul(float2 a, float2 b){ return make_float2(a.x*b.x-a.y*b.y, a.x*b.y+a.y*b.x); }
// a * conj(b)
__device__ __forceinline__ float2 cmulc(float2 a, float2 b){ return make_float2(a.x*b.x+a.y*b.y, a.y*b.x-a.x*b.y); }

#define C4 0.70710678118654752f
#define C8 0.92387953251128674f
#define S8 0.38268343236508977f
#define TWO_PI 6.28318530717958648f

// DIF 16-pt: natural input, output reg r holds X[bitrev4(r)]
__device__ __forceinline__ void fft16_dif(float2 v[16]) {
  const float twr[8] = {1.f, C8, C4, S8, 0.f, -S8, -C4, -C8};
  const float twi[8] = {0.f, -S8, -C4, -C8, -1.f, -C8, -C4, -S8};
#pragma unroll
  for (int i = 0; i < 8; ++i) {                       // m=8
    float2 a = v[i], b = v[i+8];
    v[i] = cadd(a, b);
    float2 d = csub(a, b);
    v[i+8] = make_float2(d.x*twr[i]-d.y*twi[i], d.x*twi[i]+d.y*twr[i]);
  }
#pragma unroll
  for (int blk = 0; blk < 16; blk += 8)               // m=4
#pragma unroll
    for (int i = 0; i < 4; ++i) {
      float2 a = v[blk+i], b = v[blk+i+4];
      v[blk+i] = cadd(a, b);
      float2 d = csub(a, b);
      v[blk+i+4] = make_float2(d.x*twr[2*i]-d.y*twi[2*i], d.x*twi[2*i]+d.y*twr[2*i]);
    }
#pragma unroll
  for (int blk = 0; blk < 16; blk += 4) {             // m=2 (tw: 1, -i)
    { float2 a = v[blk],   b = v[blk+2]; v[blk] = cadd(a,b);   v[blk+2] = csub(a,b); }
    { float2 a = v[blk+1], b = v[blk+3]; float2 d = csub(a,b);
      v[blk+1] = cadd(a,b); v[blk+3] = make_float2(d.y, -d.x); }
  }
#pragma unroll
  for (int blk = 0; blk < 16; blk += 2) {             // m=1
    float2 a = v[blk], b = v[blk+1];
    v[blk] = cadd(a, b); v[blk+1] = csub(a, b);
  }
}

// same but input v[8..15] known zero (zero-padded signal)
__device__ __forceinline__ void fft16_dif_zero8(float2 v[16]) {
  const float twr[8] = {1.f, C8, C4, S8, 0.f, -S8, -C4, -C8};
  const float twi[8] = {0.f, -S8, -C4, -C8, -1.f, -C8, -C4, -S8};
#pragma unroll
  for (int i = 1; i < 8; ++i) {                       // m=8, b=0
    float2 a = v[i];
    v[i+8] = make_float2(a.x*twr[i]-a.y*twi[i], a.x*twi[i]+a.y*twr[i]);
  }
  v[8] = v[0];
#pragma unroll
  for (int blk = 0; blk < 16; blk += 8)               // m=4
#pragma unroll
    for (int i = 0; i < 4; ++i) {
      float2 a = v[blk+i], b = v[blk+i+4];
      v[blk+i] = cadd(a, b);
      float2 d = csub(a, b);
      v[blk+i+4] = make_float2(d.x*twr[2*i]-d.y*twi[2*i], d.x*twi[2*i]+d.y*twr[2*i]);
    }
#pragma unroll
  for (int blk = 0; blk < 16; blk += 4) {             // m=2
    { float2 a = v[blk],   b = v[blk+2]; v[blk] = cadd(a,b);   v[blk+2] = csub(a,b); }
    { float2 a = v[blk+1], b = v[blk+3]; float2 d = csub(a,b);
      v[blk+1] = cadd(a,b); v[blk+3] = make_float2(d.y, -d.x); }
  }
#pragma unroll
  for (int blk = 0; blk < 16; blk += 2) {             // m=1
    float2 a = v[blk], b = v[blk+1];
    v[blk] = cadd(a, b); v[blk+1] = csub(a, b);
  }
}

// conj-transpose mirror (unnormalized): input reg r = X[bitrev4(r)],
// output natural y[n] = sum_k X[k] W^{+nk}
__device__ __forceinline__ void idft16(float2 v[16]) {
  const float twr[8] = {1.f, C8, C4, S8, 0.f, -S8, -C4, -C8};
  const float twi[8] = {0.f, S8, C4, C8, 1.f, C8, C4, S8};     // conj
#pragma unroll
  for (int blk = 0; blk < 16; blk += 2) {             // m=1
    float2 a = v[blk], b = v[blk+1];
    v[blk] = cadd(a, b); v[blk+1] = csub(a, b);
  }
#pragma unroll
  for (int blk = 0; blk < 16; blk += 4) {             // m=2 (tw: 1, +i)
    { float2 a = v[blk],   b = v[blk+2]; v[blk] = cadd(a,b);   v[blk+2] = csub(a,b); }
    { float2 a = v[blk+1], b = v[blk+3]; float2 t = make_float2(-b.y, b.x);
      v[blk+1] = cadd(a,t); v[blk+3] = csub(a,t); }
  }
#pragma unroll
  for (int blk = 0; blk < 16; blk += 8)               // m=4
#pragma unroll
    for (int i = 0; i < 4; ++i) {
      float2 b = v[blk+i+4];
      float2 t = make_float2(b.x*twr[2*i]-b.y*twi[2*i], b.x*twi[2*i]+b.y*twr[2*i]);
      float2 a = v[blk+i];
      v[blk+i] = cadd(a, t); v[blk+i+4] = csub(a, t);
    }
#pragma unroll
  for (int i = 0; i < 8; ++i) {                       // m=8
    float2 b = v[i+8];
    float2 t = make_float2(b.x*twr[i]-b.y*twi[i], b.x*twi[i]+b.y*twr[i]);
    float2 a = v[i];
    v[i] = cadd(a, t); v[i+8] = csub(a, t);
  }
}

// idft16 but only outputs 0..7 needed: last stage skips subtract half
__device__ __forceinline__ void idft16_low8(float2 v[16]) {
  const float twr[8] = {1.f, C8, C4, S8, 0.f, -S8, -C4, -C8};
  const float twi[8] = {0.f, S8, C4, C8, 1.f, C8, C4, S8};
#pragma unroll
  for (int blk = 0; blk < 16; blk += 2) {
    float2 a = v[blk], b = v[blk+1];
    v[blk] = cadd(a, b); v[blk+1] = csub(a, b);
  }
#pragma unroll
  for (int blk = 0; blk < 16; blk += 4) {
    { float2 a = v[blk],   b = v[blk+2]; v[blk] = cadd(a,b);   v[blk+2] = csub(a,b); }
    { float2 a = v[blk+1], b = v[blk+3]; float2 t = make_float2(-b.y, b.x);
      v[blk+1] = cadd(a,t); v[blk+3] = csub(a,t); }
  }
#pragma unroll
  for (int blk = 0; blk < 16; blk += 8)
#pragma unroll
    for (int i = 0; i < 4; ++i) {
      float2 b = v[blk+i+4];
      float2 t = make_float2(b.x*twr[2*i]-b.y*twi[2*i], b.x*twi[2*i]+b.y*twr[2*i]);
      float2 a = v[blk+i];
      v[blk+i] = cadd(a, t); v[blk+i+4] = csub(a, t);
    }
#pragma unroll
  for (int i = 0; i < 8; ++i) {                       // m=8: only y[i]=a+t
    float2 b = v[i+8];
    float2 t = make_float2(b.x*twr[i]-b.y*twi[i], b.x*twi[i]+b.y*twr[i]);
    v[i] = cadd(v[i], t);
  }
}

#define BR_TABLE {0,8,4,12,2,10,6,14,1,9,5,13,3,11,7,15}
#define PAD(i) ((i) + ((i) >> 4))

// ---------------- MiT[d][e] = bf16(Mi[e][d]), LDS-tiled ----------------
__global__ __launch_bounds__(256) void transpose_cast_Mi(const float* __restrict__ Mi,
                                                         unsigned short* __restrict__ MiT) {
  __shared__ float tile[64][65];
  const int d0 = blockIdx.x * 64;
  const int e0 = blockIdx.y * 64;
  const int tid = threadIdx.x;
#pragma unroll
  for (int i = 0; i < 16; ++i) {
    int ee = (tid >> 6) + i * 4;
    int dd = tid & 63;
    tile[ee][dd] = Mi[(e0 + ee) * ND + d0 + dd];
  }
  __syncthreads();
#pragma unroll
  for (int i = 0; i < 8; ++i) {
    int dd = (tid >> 5) + i * 8;
    int ee2 = (tid & 31) * 2;
    unsigned int w = (unsigned int)f2bf(tile[ee2][dd]) |
                     ((unsigned int)f2bf(tile[ee2 + 1][dd]) << 16);
    *(unsigned int*)(MiT + (size_t)(d0 + dd) * ND + e0 + ee2) = w;
  }
}

// ---------------- GEMM: x_projT[b,d,s] = bf16( sum_e x[b,s,e] Mi[e,d] ) ----------------
// fp32 A read direct (cast fused into staging); 2-phase prefetch, dbuf LDS;
// B via global_load_lds; XCD-chunk swizzle; LDS-staged coalesced C-write.
__global__ __launch_bounds__(256) void gemm_xprojT(const float* __restrict__ Xf,
                                                   const unsigned short* __restrict__ MiT,
                                                   unsigned short* __restrict__ XPT) {
  __shared__ __align__(16) unsigned char smem[33792];   // dbuf A/B (32KB) or Cb (33KB)
  unsigned short* As0 = (unsigned short*)smem;          // 4096 shorts each
  unsigned short* Bs0 = As0 + 4096;
  unsigned short* As1 = Bs0 + 4096;
  unsigned short* Bs1 = As1 + 4096;

  const int tid = threadIdx.x;
  const int lane = tid & 63;
  const int wave = tid >> 6;
  // bijective XCD-chunk swizzle: 768 blocks, 96/XCD; within a chunk c0 varies
  // fastest so the 6 blocks sharing one A-panel co-run on one XCD.
  const int f = blockIdx.x;
  const int swz = (f & 7) * 96 + (f >> 3);
  const int c0 = (swz % 6) * 128;       // d
  const int r0 = (swz / 6) * 128;       // global row in [0,16384)

  // A staging geometry: thread covers rows rowA and rowA+64, 8 floats each
  const int rowA = tid >> 2;            // 0..63
  const int colq = (tid & 3) * 8;       // 0,8,16,24

  f32x4 acc[4][4];
#pragma unroll
  for (int m = 0; m < 4; ++m)
#pragma unroll
    for (int n = 0; n < 4; ++n) acc[m][n] = (f32x4){0.f, 0.f, 0.f, 0.f};

  // ---- prologue: stage tile 0 into buf0 ----
  {
    const float* ga = Xf + (size_t)(r0 + rowA) * ND + colq;
    float4 p0 = *(const float4*)ga, p1 = *(const float4*)(ga + 4);
    const float* ga2 = ga + (size_t)64 * ND;
    float4 p2 = *(const float4*)ga2, p3 = *(const float4*)(ga2 + 4);
#pragma unroll
    for (int h = 0; h < 2; ++h) {
      int c = wave * 2 + h;
      int rowc = c * 16 + (lane >> 2);
      const unsigned short* gb = MiT + (size_t)(c0 + rowc) * ND + (lane & 3) * 8;
      __builtin_amdgcn_global_load_lds(
          (const __attribute__((address_space(1))) void*)gb,
          (__attribute__((address_space(3))) void*)(Bs0 + c * 512), 16, 0, 0);
    }
    unsigned int w0 = (unsigned int)f2bf(p0.x) | ((unsigned int)f2bf(p0.y) << 16);
    unsigned int w1 = (unsigned int)f2bf(p0.z) | ((unsigned int)f2bf(p0.w) << 16);
    unsigned int w2 = (unsigned int)f2bf(p1.x) | ((unsigned int)f2bf(p1.y) << 16);
    unsigned int w3 = (unsigned int)f2bf(p1.z) | ((unsigned int)f2bf(p1.w) << 16);
    *(uint4*)(As0 + tid * 8) = make_uint4(w0, w1, w2, w3);
    w0 = (unsigned int)f2bf(p2.x) | ((unsigned int)f2bf(p2.y) << 16);
    w1 = (unsigned int)f2bf(p2.z) | ((unsigned int)f2bf(p2.w) << 16);
    w2 = (unsigned int)f2bf(p3.x) | ((unsigned int)f2bf(p3.y) << 16);
    w3 = (unsigned int)f2bf(p3.z) | ((unsigned int)f2bf(p3.w) << 16);
    *(uint4*)(As0 + 2048 + tid * 8) = make_uint4(w0, w1, w2, w3);
  }
  __syncthreads();

  // ---- main loop: prefetch t+1 while computing t ----
  for (int t = 0; t < NK; ++t) {
    unsigned short* Ac = (t & 1) ? As1 : As0;
    unsigned short* Bc = (t & 1) ? Bs1 : Bs0;
    unsigned short* An = (t & 1) ? As0 : As1;
    unsigned short* Bn = (t & 1) ? Bs0 : Bs1;
    const bool pre = (t < NK - 1);
    float4 p0, p1, p2, p3;
    if (pre) {
      const int k0n = (t + 1) * 32;
      const float* ga = Xf + (size_t)(r0 + rowA) * ND + k0n + colq;
      p0 = *(const float4*)ga; p1 = *(const float4*)(ga + 4);
      const float* ga2 = ga + (size_t)64 * ND;
      p2 = *(const float4*)ga2; p3 = *(const float4*)(ga2 + 4);
#pragma unroll
      for (int h = 0; h < 2; ++h) {
        int c = wave * 2 + h;
        int rowc = c * 16 + (lane >> 2);
        const unsigned short* gb = MiT + (size_t)(c0 + rowc) * ND + k0n + (lane & 3) * 8;
        __builtin_amdgcn_global_load_lds(
            (const __attribute__((address_space(1))) void*)gb,
            (__attribute__((address_space(3))) void*)(Bn + c * 512), 16, 0, 0);
      }
    }

    const int wr = (wave >> 1) * 64;
    const int wc = (wave & 1) * 64;
    short8 a[4], b[4];
#pragma unroll
    for (int m = 0; m < 4; ++m)
      a[m] = *(const short8*)(Ac + (wr + m * 16 + (lane & 15)) * 32 + (lane >> 4) * 8);
#pragma unroll
    for (int n = 0; n < 4; ++n)
      b[n] = *(const short8*)(Bc + (wc + n * 16 + (lane & 15)) * 32 + (lane >> 4) * 8);
#pragma unroll
    for (int m = 0; m < 4; ++m)
#pragma unroll
      for (int n = 0; n < 4; ++n)
        acc[m][n] = __builtin_amdgcn_mfma_f32_16x16x32_bf16(a[m], b[n], acc[m][n], 0, 0, 0);

    if (pre) {
      unsigned int w0 = (unsigned int)f2bf(p0.x) | ((unsigned int)f2bf(p0.y) << 16);
      unsigned int w1 = (unsigned int)f2bf(p0.z) | ((unsigned int)f2bf(p0.w) << 16);
      unsigned int w2 = (unsigned int)f2bf(p1.x) | ((unsigned int)f2bf(p1.y) << 16);
      unsigned int w3 = (unsigned int)f2bf(p1.z) | ((unsigned int)f2bf(p1.w) << 16);
      *(uint4*)(An + tid * 8) = make_uint4(w0, w1, w2, w3);
      w0 = (unsigned int)f2bf(p2.x) | ((unsigned int)f2bf(p2.y) << 16);
      w1 = (unsigned int)f2bf(p2.z) | ((unsigned int)f2bf(p2.w) << 16);
      w2 = (unsigned int)f2bf(p3.x) | ((unsigned int)f2bf(p3.y) << 16);
      w3 = (unsigned int)f2bf(p3.z) | ((unsigned int)f2bf(p3.w) << 16);
      *(uint4*)(An + 2048 + tid * 8) = make_uint4(w0, w1, w2, w3);
      __syncthreads();                  // drains gload_lds + ds_write for tile t+1
    }
  }
  __syncthreads();                      // all waves done with staging buffers

  // epilogue: bf16-pack into LDS (pitch 66 dwords), then coalesced writes
  unsigned int* Cb = (unsigned int*)smem;   // [128 cols][66]
  const int wr = (wave >> 1) * 64;
  const int wc = (wave & 1) * 64;
#pragma unroll
  for (int m = 0; m < 4; ++m)
#pragma unroll
    for (int n = 0; n < 4; ++n) {
      int col = wc + n * 16 + (lane & 15);
      int sp = (wr + m * 16 + (lane >> 4) * 4) >> 1;   // even
      f32x4 a4 = acc[m][n];
      unsigned int w0 = (unsigned int)f2bf(a4[0]) | ((unsigned int)f2bf(a4[1]) << 16);
      unsigned int w1 = (unsigned int)f2bf(a4[2]) | ((unsigned int)f2bf(a4[3]) << 16);
      *(uint2*)(Cb + col * 66 + sp) = make_uint2(w0, w1);
    }
  __syncthreads();
  const int bI = r0 >> 12;
  const int sBase = r0 & (NS - 1);
  {
    int col = tid >> 1, half = tid & 1;
    const unsigned int* srcl = Cb + col * 66 + half * 32;
    unsigned int* dstg = (unsigned int*)(XPT + ((size_t)bI * ND + c0 + col) * NS + sBase) + half * 32;
#pragma unroll
    for (int k = 0; k < 8; ++k)
      *(uint4*)(dstg + k * 4) = *(const uint4*)(srcl + k * 4);
  }
}

// ---------------- filter spectra (fused phi projection, LDS twiddle tables) ----------------
__global__ __launch_bounds__(256) void filter_fft(const float* __restrict__ phi,
                                                  const float* __restrict__ Mf,
                                                  float2* __restrict__ Hbr) {
  __shared__ float LR[4352], LI[4352];
  __shared__ float2 TA[256], TB[256];
  const int d = blockIdx.x;
  const int tid = threadIdx.x;
  const int BR[16] = BR_TABLE;
  float2 v[16];

  {
    float sn, cs;
    __sincosf(-(TWO_PI / 4096.f) * (float)tid, &sn, &cs); TA[tid] = make_float2(cs, sn);
    __sincosf(-(TWO_PI / 256.f) * (float)tid, &sn, &cs);  TB[tid] = make_float2(cs, sn);
  }

  float mf[NK];
#pragma unroll
  for (int k = 0; k < NK; ++k) mf[k] = Mf[k * ND + d];
#pragma unroll
  for (int n2 = 0; n2 < 8; ++n2) {
    int m = n2 * 256 + tid;            // 0..2047
    const float* pr = phi + (size_t)(2 * m) * NK;
    float acc = 0.f;
#pragma unroll
    for (int k = 0; k < NK; ++k) acc += pr[k] * mf[k];
    v[n2] = make_float2(acc, 0.f);
  }
#pragma unroll
  for (int n2 = 8; n2 < 16; ++n2) v[n2] = make_float2(0.f, 0.f);

  fft16_dif_zero8(v);
  __syncthreads();                     // tables ready
  const int t1 = tid >> 4, t0 = tid & 15;
  // P1 twiddle: W_4096^{p*tid} = TB[p*t1] * TA[p*t0]
#pragma unroll
  for (int p = 1; p < 16; ++p) v[BR[p]] = cmul(v[BR[p]], cmul(TB[p * t1], TA[p * t0]));
#pragma unroll
  for (int r = 0; r < 16; ++r) { int i = BR[r] * 256 + tid; int s = PAD(i); LR[s] = v[r].x; LI[s] = v[r].y; }
  __syncthreads();

  // P2: thread (pa,n0), DFT over n1 -> pb, twiddle W_256^{n0*pb} = TB[n0*pb]
  const int p2 = tid >> 4, n0 = tid & 15;
#pragma unroll
  for (int n1 = 0; n1 < 16; ++n1) { int i = p2 * 256 + n1 * 16 + n0; int s = PAD(i); v[n1] = make_float2(LR[s], LI[s]); }
  fft16_dif(v);
#pragma unroll
  for (int p = 1; p < 16; ++p) v[BR[p]] = cmul(v[BR[p]], TB[p * n0]);
  __syncthreads();
#pragma unroll
  for (int r = 0; r < 16; ++r) { int i = p2 * 256 + BR[r] * 16 + n0; int s = PAD(i); LR[s] = v[r].x; LI[s] = v[r].y; }
  __syncthreads();

  // P3: thread (pa,pb)=tid, DFT over n0 -> pc (regs); store lane-coalesced
#pragma unroll
  for (int q = 0; q < 16; ++q) { int i = tid * 16 + q; int s = PAD(i); v[q] = make_float2(LR[s], LI[s]); }
  fft16_dif(v);
  const float sc = 2.0f / 4096.0f;
  float2* H = Hbr + (size_t)d * 4096;
#pragma unroll
  for (int r = 0; r < 16; ++r)
    H[r * 256 + tid] = make_float2(v[r].x * sc, v[r].y * sc);
}

// ---------------- main conv: one (b,d) per workgroup ----------------
__global__ __launch_bounds__(256) void conv_kernel(const unsigned short* __restrict__ XPT,
                                                   const float2* __restrict__ Hbr,
                                                   unsigned int* __restrict__ outTb) {
  __shared__ float LR[4352], LI[4352];
  __shared__ float2 TA[256], TB[256];
  const int bd = blockIdx.x;
  const int d = bd % ND;
  const int tid = threadIdx.x;
  const int BR[16] = BR_TABLE;
  float2 v[16];

  {
    float sn, cs;
    __sincosf(-(TWO_PI / 4096.f) * (float)tid, &sn, &cs); TA[tid] = make_float2(cs, sn);
    __sincosf(-(TWO_PI / 256.f) * (float)tid, &sn, &cs);  TB[tid] = make_float2(cs, sn);
  }

  // load: z[n] = (x[2n], x[2n+1]) bf16 pair as one dword; n >= 2048 zero
  const unsigned int* src = (const unsigned int*)(XPT + (size_t)bd * NS);
#pragma unroll
  for (int n2 = 0; n2 < 8; ++n2) {
    unsigned int w = src[n2 * 256 + tid];
    v[n2] = make_float2(bf2f((unsigned short)(w & 0xffffu)), bf2f((unsigned short)(w >> 16)));
  }
#pragma unroll
  for (int n2 = 8; n2 < 16; ++n2) v[n2] = make_float2(0.f, 0.f);

  // ---- forward P1 ----
  fft16_dif_zero8(v);
  __syncthreads();                     // twiddle tables ready
  const int t1 = tid >> 4, t0 = tid & 15;
#pragma unroll
  for (int p = 1; p < 16; ++p) v[BR[p]] = cmul(v[BR[p]], cmul(TB[p * t1], TA[p * t0]));
#pragma unroll
  for (int r = 0; r < 16; ++r) { int i = BR[r] * 256 + tid; int s = PAD(i); LR[s] = v[r].x; LI[s] = v[r].y; }
  __syncthreads();

  // ---- forward P2 ----
  const int p2 = tid >> 4, n0 = tid & 15;
#pragma unroll
  for (int n1 = 0; n1 < 16; ++n1) { int i = p2 * 256 + n1 * 16 + n0; int s = PAD(i); v[n1] = make_float2(LR[s], LI[s]); }
  fft16_dif(v);
#pragma unroll
  for (int p = 1; p < 16; ++p) v[BR[p]] = cmul(v[BR[p]], TB[p * n0]);
  __syncthreads();
#pragma unroll
  for (int r = 0; r < 16; ++r) { int i = p2 * 256 + BR[r] * 16 + n0; int s = PAD(i); LR[s] = v[r].x; LI[s] = v[r].y; }
  __syncthreads();

  // ---- forward P3 + pointwise*H + inverse PA: all in registers ----
#pragma unroll
  for (int q = 0; q < 16; ++q) { int i = tid * 16 + q; int s = PAD(i); v[q] = make_float2(LR[s], LI[s]); }
  fft16_dif(v);
  const float2* H = Hbr + (size_t)d * 4096;
#pragma unroll
  for (int r = 0; r < 16; ++r) v[r] = cmul(v[r], H[r * 256 + tid]);
  idft16(v);                                   // -> natural over pc-axis
  // PA twiddle: conj(W_256^{n*pb}), pb = tid&15
#pragma unroll
  for (int n = 1; n < 16; ++n) v[n] = cmulc(v[n], TB[n * (tid & 15)]);
#pragma unroll
  for (int n = 0; n < 16; ++n) { int i = tid * 16 + n; int s = PAD(i); LR[s] = v[n].x; LI[s] = v[n].y; }
  __syncthreads();

  // ---- inverse PB: thread (pa,n0), IDFT over pb -> n1 ----
#pragma unroll
  for (int r = 0; r < 16; ++r) { int i = p2 * 256 + BR[r] * 16 + n0; int s = PAD(i); v[r] = make_float2(LR[s], LI[s]); }
  idft16(v);                                   // -> natural n1
  // PB twiddle: conj(W_4096^{pa(16n+n0)}) = conj(TB[pa*n] * TA[pa*n0])
  {
    float2 cA = TA[p2 * n0];
#pragma unroll
    for (int n = 0; n < 16; ++n) v[n] = cmulc(v[n], cmul(TB[p2 * n], cA));
  }
  __syncthreads();
#pragma unroll
  for (int n = 0; n < 16; ++n) { int i = p2 * 256 + n * 16 + n0; int s = PAD(i); LR[s] = v[n].x; LI[s] = v[n].y; }
  __syncthreads();

  // ---- inverse PC: thread tid, IDFT over pa -> natural n2 (only n2<8 needed) ----
#pragma unroll
  for (int r = 0; r < 16; ++r) { int i = BR[r] * 256 + tid; int s = PAD(i); v[r] = make_float2(LR[s], LI[s]); }
  idft16_low8(v);
  unsigned int* dst = outTb + (size_t)bd * 2048;    // dword = (out[2n], out[2n+1]) bf16
#pragma unroll
  for (int n2 = 0; n2 < 8; ++n2) {
    float2 y = v[n2];
    unsigned int w = (unsigned int)f2bf(y.x) | ((unsigned int)f2bf(y.y) << 16);
    dst[(n2 << 8) + tid] = w;
  }
}

// ---------------- transpose outTb (B,D,S) bf16 -> out (B,S,D) fp32 ----------------
__global__ __launch_bounds__(256) void transpose_out(const unsigned int* __restrict__ outTb,
                                                     float* __restrict__ out) {
  __shared__ float tile[64][65];
  const int b = blockIdx.z;
  const int d0 = blockIdx.y * 64;
  const int s0 = blockIdx.x * 64;
  const int tid = threadIdx.x;
#pragma unroll
  for (int i = 0; i < 8; ++i) {
    int dd = (tid >> 5) + i * 8;
    int ss2 = (tid & 31) * 2;
    unsigned int w = outTb[(((size_t)b * ND + d0 + dd) * NS + s0 + ss2) >> 1];
    tile[dd][ss2]     = bf2f((unsigned short)(w & 0xffffu));
    tile[dd][ss2 + 1] = bf2f((unsigned short)(w >> 16));
  }
  __syncthreads();
#pragma unroll
  for (int i = 0; i < 16; ++i) {
    int ss = (tid >> 6) + i * 4;
    int dd = tid & 63;
    out[((size_t)b * NS + s0 + ss) * ND + d0 + dd] = tile[dd][ss];
  }
}

extern "C" void kernel_launch(void* const* d_in, const int* in_sizes, int n_in,
                              void* d_out, int out_size, void* d_ws, size_t ws_size,
                              hipStream_t stream) {
  const float* x   = (const float*)d_in[0];
  const float* phi = (const float*)d_in[1];
  const float* Mi  = (const float*)d_in[2];
  const float* Mf  = (const float*)d_in[3];
  float* out = (float*)d_out;

  // ws (96 MB): XPT bf16 @0 (24M) | Hbr @24M (24M) | pool @48M (48M)
  // pool: outTb bf16 @0 (24M) | MiT @24M
  const size_t SZ_XPT = (size_t)NB * ND * NS * 2;        // 24 MB
  const size_t SZ_HBR = (size_t)ND * 4096 * 8;           // 24 MB
  const size_t SZ_POOL = (size_t)NB * ND * NS * 4;       // 48 MB
  if (ws_size < SZ_XPT + SZ_HBR + SZ_POOL) return;

  char* ws = (char*)d_ws;
  unsigned short* xprojT = (unsigned short*)ws;
  float2* Hbr = (float2*)(ws + SZ_XPT);
  char* pool = ws + SZ_XPT + SZ_HBR;
  unsigned int* outTb = (unsigned int*)pool;
  unsigned short* MiT = (unsigned short*)(pool + 25165824);

  transpose_cast_Mi<<<dim3(ND / 64, ND / 64), 256, 0, stream>>>(Mi, MiT);
  gemm_xprojT<<<768, 256, 0, stream>>>(x, MiT, xprojT);
  filter_fft<<<ND, 256, 0, stream>>>(phi, Mf, Hbr);
  conv_kernel<<<NB * ND, 256, 0, stream>>>(xprojT, Hbr, outTb);
  transpose_out<<<dim3(NS / 64, ND / 64, NB), 256, 0, stream>>>(outTb, out);
}